// Round 8
// baseline (370.810 us; speedup 1.0000x reference)
//
#include <hip/hip_runtime.h>
#include <math.h>

// Problem constants
#define B_  2
#define S_  2048
#define D_  2048
#define H_  16
#define HD_ 128

using u16 = unsigned short;
using u32 = unsigned int;
typedef __attribute__((ext_vector_type(4))) float f32x4;
typedef __attribute__((ext_vector_type(8))) short bf16x8;   // 8 bf16 = 4 VGPRs (MFMA A/B frag)
using u16x4_t = __attribute__((ext_vector_type(4))) unsigned short;
using u16x8_t = __attribute__((ext_vector_type(8))) unsigned short;
typedef __attribute__((ext_vector_type(2))) u32 u32x2;
typedef __attribute__((ext_vector_type(4))) u32 u32x4;

__device__ __forceinline__ u16 f2bf(float f) {
  u32 u = __builtin_bit_cast(u32, f);
  u32 r = u + 0x7fffu + ((u >> 16) & 1u);   // RNE
  return (u16)(r >> 16);
}
__device__ __forceinline__ float bf2f(u16 x) {
  u32 u = ((u32)x) << 16;
  return __builtin_bit_cast(float, u);
}
// async global->LDS, 16B per lane; LDS dest = wave-uniform base + lane*16;
// global source address is PER-LANE (enables source-side swizzling).
__device__ __forceinline__ void async_copy16(const u16* g, u16* l) {
  __builtin_amdgcn_global_load_lds((const __attribute__((address_space(1))) u32*)g,
                                   (__attribute__((address_space(3))) u32*)l, 16, 0, 0);
}

// ---------------- fp32 -> bf16 convert ----------------
__global__ void cvt_f32_bf16(const float* __restrict__ src, u16* __restrict__ dst, int n) {
  int i = (blockIdx.x * blockDim.x + threadIdx.x) * 4;
  if (i >= n) return;
  float4 v = *(const float4*)(src + i);
  u16x4_t o;
  o[0] = f2bf(v.x); o[1] = f2bf(v.y); o[2] = f2bf(v.z); o[3] = f2bf(v.w);
  *(u16x4_t*)(dst + i) = o;
}

// ---------------- RoPE cos/sin table ----------------
__global__ void rope_table(const int* __restrict__ pos, float2* __restrict__ tab) {
  int t = blockIdx.x * blockDim.x + threadIdx.x;  // S*64
  if (t >= S_ * 64) return;
  int s = t >> 6, i = t & 63;
  float freq = expf(-(float)i * (9.210340371976184f / 64.0f));  // theta^{-i/64}
  float ang = (float)pos[s] * freq;
  tab[t] = make_float2(cosf(ang), sinf(ang));
}

// ---------------- RoPE apply (in-place, Q and K) ----------------
__global__ void rope_apply(u16* __restrict__ Q, u16* __restrict__ K,
                           const float2* __restrict__ tab) {
  int t = blockIdx.x * blockDim.x + threadIdx.x;  // B*S*H*16
  int g = t & 15;
  int bsh = t >> 4;
  int h = bsh & (H_ - 1);
  int bs = bsh >> 4;            // b*S + s
  int s = bs & (S_ - 1);
  size_t base = (size_t)bs * D_ + (size_t)h * HD_;
  int d2 = g * 4;
  const float2* tb = &tab[s * 64 + d2];
  float2 cs[4];
  #pragma unroll
  for (int j = 0; j < 4; ++j) cs[j] = tb[j];
  #pragma unroll
  for (int which = 0; which < 2; ++which) {
    u16* P = which ? K : Q;
    u16x4_t a = *(u16x4_t*)(P + base + d2);
    u16x4_t c = *(u16x4_t*)(P + base + 64 + d2);
    u16x4_t ra, rc;
    #pragma unroll
    for (int j = 0; j < 4; ++j) {
      float t1 = bf2f(a[j]), t2 = bf2f(c[j]);
      ra[j] = f2bf(t1 * cs[j].x - t2 * cs[j].y);
      rc[j] = f2bf(t1 * cs[j].y + t2 * cs[j].x);
    }
    *(u16x4_t*)(P + base + d2) = ra;
    *(u16x4_t*)(P + base + 64 + d2) = rc;
  }
}

// ---------------- GEMM: C = A(MxK) * Bt(NxK)^T, bf16 in, fp32 acc ----------------
// m97 structure: 128x128 tile, BK=32, 4 waves x (4x4) 16x16x32 MFMA, global_load_lds staging.
template <bool F32OUT>
__global__ void gemm_bt(const u16* __restrict__ A, const u16* __restrict__ Bt,
                        void* __restrict__ Cout, int M, int N, int K) {
  __shared__ u16 lA[128 * 32];
  __shared__ u16 lB[128 * 32];
  const int tid = threadIdx.x;
  const int lane = tid & 63;
  const int w = tid >> 6;            // wave 0..3
  const int wr = w >> 1, wc = w & 1; // 2x2 waves of 64x64
  const int bm = blockIdx.x * 128;
  const int bn = blockIdx.y * 128;
  const int fr = lane & 15, fq = lane >> 4;
  f32x4 acc[4][4] = {};
  for (int k0 = 0; k0 < K; k0 += 32) {
    // stage: 8 chunks of 1KB per matrix; wave w does chunks {w, w+4}
    #pragma unroll
    for (int c = w; c < 8; c += 4) {
      const int e = c * 512 + lane * 8;       // element offset in [128][32] tile
      const int r = e >> 5, col = e & 31;
      async_copy16(A + (size_t)(bm + r) * K + k0 + col, lA + c * 512);
      async_copy16(Bt + (size_t)(bn + r) * K + k0 + col, lB + c * 512);
    }
    __syncthreads();   // drains vmcnt
    bf16x8 af[4], bfr[4];
    #pragma unroll
    for (int i = 0; i < 4; ++i) {
      af[i]  = *(const bf16x8*)&lA[(wr * 64 + i * 16 + fr) * 32 + fq * 8];
      bfr[i] = *(const bf16x8*)&lB[(wc * 64 + i * 16 + fr) * 32 + fq * 8];
    }
    #pragma unroll
    for (int i = 0; i < 4; ++i)
      #pragma unroll
      for (int j = 0; j < 4; ++j)
        acc[i][j] = __builtin_amdgcn_mfma_f32_16x16x32_bf16(af[i], bfr[j], acc[i][j], 0, 0, 0);
    __syncthreads();
  }
  // C/D layout: col = lane&15, row = (lane>>4)*4 + reg  [m89/m91 verified]
  #pragma unroll
  for (int i = 0; i < 4; ++i)
    #pragma unroll
    for (int j = 0; j < 4; ++j) {
      const int row = bm + wr * 64 + i * 16 + fq * 4;
      const int col = bn + wc * 64 + j * 16 + fr;
      #pragma unroll
      for (int r = 0; r < 4; ++r) {
        const float v = acc[i][j][r];
        if (F32OUT) ((float*)Cout)[(size_t)(row + r) * N + col] = v;
        else        ((u16*)Cout)[(size_t)(row + r) * N + col] = f2bf(v);
      }
    }
}

// ---------------- fused QKV GEMM: Bt is packed [6144][2048] (Wq;Wk;Wv) ----------------
// Same m97 structure; output routed to Q/K/V by bn>>11. 1536 blocks = 6/CU. (round-5 proven)
__global__ void gemm_qkv3(const u16* __restrict__ A, const u16* __restrict__ Bt,
                          u16* __restrict__ Qo, u16* __restrict__ Ko, u16* __restrict__ Vo) {
  __shared__ u16 lA[128 * 32];
  __shared__ u16 lB[128 * 32];
  const int tid = threadIdx.x;
  const int lane = tid & 63;
  const int w = tid >> 6;
  const int wr = w >> 1, wc = w & 1;
  const int bm = blockIdx.x * 128;
  const int bn = blockIdx.y * 128;          // 0..6016
  const int fr = lane & 15, fq = lane >> 4;
  const int K = D_;
  f32x4 acc[4][4] = {};
  for (int k0 = 0; k0 < K; k0 += 32) {
    #pragma unroll
    for (int c = w; c < 8; c += 4) {
      const int e = c * 512 + lane * 8;
      const int r = e >> 5, col = e & 31;
      async_copy16(A + (size_t)(bm + r) * K + k0 + col, lA + c * 512);
      async_copy16(Bt + (size_t)(bn + r) * K + k0 + col, lB + c * 512);
    }
    __syncthreads();
    bf16x8 af[4], bfr[4];
    #pragma unroll
    for (int i = 0; i < 4; ++i) {
      af[i]  = *(const bf16x8*)&lA[(wr * 64 + i * 16 + fr) * 32 + fq * 8];
      bfr[i] = *(const bf16x8*)&lB[(wc * 64 + i * 16 + fr) * 32 + fq * 8];
    }
    #pragma unroll
    for (int i = 0; i < 4; ++i)
      #pragma unroll
      for (int j = 0; j < 4; ++j)
        acc[i][j] = __builtin_amdgcn_mfma_f32_16x16x32_bf16(af[i], bfr[j], acc[i][j], 0, 0, 0);
    __syncthreads();
  }
  u16* out = (bn < 2048) ? Qo : (bn < 4096) ? Ko : Vo;
  const int bnl = bn & 2047;
  #pragma unroll
  for (int i = 0; i < 4; ++i)
    #pragma unroll
    for (int j = 0; j < 4; ++j) {
      const int row = bm + wr * 64 + i * 16 + fq * 4;
      const int col = bnl + wc * 64 + j * 16 + fr;
      #pragma unroll
      for (int r = 0; r < 4; ++r)
        out[(size_t)(row + r) * D_ + col] = f2bf(acc[i][j][r]);
    }
}

// ---------------- causal flash attention, KV-split + double-buffered pipeline ----------------
// grid: (16, B*H, 2). Block (x, bh, split): q-tiles {x, 31-x}, balanced KV ranges
// (33-34 tiles each). Round-8 structure: ONE barrier per tile, double-buffered
// lK/lV. Per tile t: barrier -> issue t+1 K-DMA + V global loads -> compute(t)
// -> write lV[nxt] from regs. Staging latency hides under compute; the barrier's
// implicit vmcnt(0) drain costs nothing (loads had the full compute to land).
// K staged via global_load_lds into LINEAR [32][128] with PRE-SWIZZLED global
// source (slot ^= row&7, 16B slots); reads apply the same XOR -> all-32-bank,
// 2-way (free). V^T reg-staged with XOR-swizzled scalar writes (round-4 proven).
#define QB 64
#define KB 32
#define PLD 36    // P row stride (72B): writes spread all 32 banks (free)

__global__ __launch_bounds__(256, 2)
void attn_fwd(const u16* __restrict__ Qg, const u16* __restrict__ Kg,
              const u16* __restrict__ Vg, u16* __restrict__ po0,
              u16* __restrict__ po1, float2* __restrict__ ml) {
  __shared__ u16 lK[2][KB * HD_];   // linear [kv][hd], source-swizzled content
  __shared__ u16 lV[2][HD_ * 40];   // swizzled V^T
  __shared__ u16 lP[4][16 * PLD];   // per-wave P 16x32
  const int tid = threadIdx.x;
  const int lane = tid & 63;
  const int w = tid >> 6;
  const int fr = lane & 15, fq = lane >> 4;
  const int bh = blockIdx.y;
  const int split = blockIdx.z;
  const size_t base = (size_t)(bh >> 4) * S_ * D_ + (size_t)(bh & 15) * HD_;
  const int xA = blockIdx.x;                 // 0..15
  const int qA = xA * QB, qB = (31 - xA) * QB;
  const int ntA = (qA + QB) / KB;            // 2..32
  const int ntB = (qB + QB) / KB;            // 34..64
  const int c = (ntA <= 16) ? (33 - ntA) : 16;   // balanced split point
  const int t0 = split ? c : 0;
  const int t1 = split ? ntB : c;
  const float kscale = 0.08838834764831843f * 1.4426950408889634f; // 1/sqrt(128)*log2e

  // Q fragments for both q-tiles (A-layout: row=lane&15, k=(lane>>4)*8+j)
  bf16x8 qfA[4], qfB[4];
  {
    const u16* qpa = Qg + base + (size_t)(qA + w * 16 + fr) * D_ + fq * 8;
    const u16* qpb = Qg + base + (size_t)(qB + w * 16 + fr) * D_ + fq * 8;
    #pragma unroll
    for (int kk = 0; kk < 4; ++kk) {
      qfA[kk] = *(const bf16x8*)(qpa + kk * 32);
      qfB[kk] = *(const bf16x8*)(qpb + kk * 32);
    }
  }
  f32x4 oA[8] = {}, oB[8] = {};
  float mA[4], lA_[4], mB[4], lB_[4];
  #pragma unroll
  for (int r = 0; r < 4; ++r) { mA[r] = mB[r] = -INFINITY; lA_[r] = lB_[r] = 0.f; }

  // K staging: wave w issues DMA chunks {w, w+4}; chunk c covers rows 4c..4c+3.
  // Lane -> (row = 4c + lane>>4, slot16 = lane&15); source col-slot = slot ^ (row&7).
  auto stageK = [&](int buf, int kv0) {
    #pragma unroll
    for (int cc = w; cc < 8; cc += 4) {
      const int row = cc * 4 + (lane >> 4);
      const int slot = (lane & 15) ^ (row & 7);
      async_copy16(Kg + base + (size_t)(kv0 + row) * D_ + slot * 8, &lK[buf][cc * 512]);
    }
  };
  // V staging: thread -> (kv row = tid>>3, 16 hd at (tid&7)*16)
  const int srow = tid >> 3, sc0 = (tid & 7) * 16;
  const u32 swz = (u32)((sc0 >> 4) & 7) << 4;
  const u32 rb = (u32)srow * 2;
  u16x8_t rv0, rv1;
  auto loadV = [&](int kv0) {
    const u16* gv = Vg + base + (size_t)(kv0 + srow) * D_ + sc0;
    rv0 = *(const u16x8_t*)gv; rv1 = *(const u16x8_t*)(gv + 8);
  };
  auto writeV = [&](int buf) {
    char* lv = (char*)&lV[buf][0];
    #pragma unroll
    for (int j = 0; j < 8; ++j) {
      *(u16*)(lv + ((((u32)(sc0 + j) * 80) + rb) ^ swz))     = rv0[j];
      *(u16*)(lv + ((((u32)(sc0 + 8 + j) * 80) + rb) ^ swz)) = rv1[j];
    }
  };

  // softmax + P-store for one q-tile's 16x32 score block (round-2/4 proven math)
  auto softmax_store = [&](const f32x4& s0, const f32x4& s1, float* mrow, float* lrow,
                           f32x4* o, int q0t, int kv0) {
    float al[4];
    const bool notfull = (kv0 + KB - 1 > q0t);
    #pragma unroll
    for (int r = 0; r < 4; ++r) {
      float v0 = s0[r] * kscale, v1 = s1[r] * kscale;
      if (notfull) {
        const int rowq = q0t + w * 16 + fq * 4 + r;
        if (kv0 + fr > rowq)      v0 = -INFINITY;
        if (kv0 + 16 + fr > rowq) v1 = -INFINITY;
      }
      float m2 = fmaxf(v0, v1);
      #pragma unroll
      for (int d = 1; d < 16; d <<= 1) m2 = fmaxf(m2, __shfl_xor(m2, d));
      const float mn = fmaxf(mrow[r], m2);
      al[r] = exp2f(mrow[r] - mn);
      mrow[r] = mn;
      const float p0 = exp2f(v0 - mn);
      const float p1 = exp2f(v1 - mn);
      float rs = p0 + p1;
      #pragma unroll
      for (int d = 1; d < 16; d <<= 1) rs += __shfl_xor(rs, d);
      lrow[r] = lrow[r] * al[r] + rs;
      lP[w][(fq * 4 + r) * PLD + fr]      = f2bf(p0);
      lP[w][(fq * 4 + r) * PLD + 16 + fr] = f2bf(p1);
    }
    #pragma unroll
    for (int nb = 0; nb < 8; ++nb)
      #pragma unroll
      for (int r = 0; r < 4; ++r) o[nb][r] *= al[r];
  };

  auto pv = [&](f32x4* o, const bf16x8* vf) {
    u32x2 pa0 = *(const u32x2*)&lP[w][fr * PLD + fq * 8];
    u32x2 pa1 = *(const u32x2*)&lP[w][fr * PLD + fq * 8 + 4];
    u32x4 pc; pc[0] = pa0[0]; pc[1] = pa0[1]; pc[2] = pa1[0]; pc[3] = pa1[1];
    const bf16x8 pa = __builtin_bit_cast(bf16x8, pc);
    #pragma unroll
    for (int nb = 0; nb < 8; ++nb)
      o[nb] = __builtin_amdgcn_mfma_f32_16x16x32_bf16(pa, vf[nb], o[nb], 0, 0, 0);
  };

  // prologue: stage tile t0 into buffer 0
  stageK(0, t0 * KB);
  loadV(t0 * KB);
  writeV(0);

  for (int t = t0; t < t1; ++t) {
    const int kv0 = t * KB;
    const int cur = (t - t0) & 1, nxt = cur ^ 1;
    __syncthreads();   // drains vmcnt/lgkmcnt: lK[cur] DMA + lV[cur] writes visible;
                       // iter t-1's readers of buffer nxt are done -> safe to refill
    if (t + 1 < t1) {
      stageK(nxt, kv0 + KB);   // async DMA, drained by next barrier
      loadV(kv0 + KB);         // regs; consumed by writeV after compute
    }

    const bool doA = (t < ntA);
    // QK^T for both q-tiles, sharing the K fragments (source-swizzled reads)
    f32x4 sA0 = {}, sA1 = {}, sB0 = {}, sB1 = {};
    #pragma unroll
    for (int kk = 0; kk < 4; ++kk) {
      const int sl = ((kk * 4 + fq) ^ (fr & 7)) * 16;
      bf16x8 k0f = *(const bf16x8*)((const char*)&lK[cur][0] + fr * 256 + sl);
      bf16x8 k1f = *(const bf16x8*)((const char*)&lK[cur][0] + (16 + fr) * 256 + sl);
      if (doA) {
        sA0 = __builtin_amdgcn_mfma_f32_16x16x32_bf16(qfA[kk], k0f, sA0, 0, 0, 0);
        sA1 = __builtin_amdgcn_mfma_f32_16x16x32_bf16(qfA[kk], k1f, sA1, 0, 0, 0);
      }
      sB0 = __builtin_amdgcn_mfma_f32_16x16x32_bf16(qfB[kk], k0f, sB0, 0, 0, 0);
      sB1 = __builtin_amdgcn_mfma_f32_16x16x32_bf16(qfB[kk], k1f, sB1, 0, 0, 0);
    }

    // V fragments (shared by both q-tiles): b128 reads, wave-uniform XOR term
    bf16x8 vf[8];
    #pragma unroll
    for (int nb = 0; nb < 8; ++nb) {
      const u32 off = (((u32)(nb * 16 + fr) * 80) + (u32)fq * 16) ^ ((u32)nb << 4);
      vf[nb] = *(const bf16x8*)((const char*)&lV[cur][0] + off);
    }

    if (doA) { softmax_store(sA0, sA1, mA, lA_, oA, qA, kv0); pv(oA, vf); }
    softmax_store(sB0, sB1, mB, lB_, oB, qB, kv0);
    pv(oB, vf);

    if (t + 1 < t1) writeV(nxt);   // after compute; vmcnt wait on rv is long past due
  }

  // epilogue: write UNNORMALIZED partials + (m,l) per row
  u16* po = split ? po1 : po0;
  float2* mlp = ml + (size_t)split * (B_ * H_ * S_) + (size_t)bh * S_;
  #pragma unroll
  for (int r = 0; r < 4; ++r) {
    const int rowA = qA + w * 16 + fq * 4 + r;
    const int rowB = qB + w * 16 + fq * 4 + r;
    if (fr == 0) {
      mlp[rowA] = make_float2(mA[r], lA_[r]);
      mlp[rowB] = make_float2(mB[r], lB_[r]);
    }
    u16* orA = po + base + (size_t)rowA * D_;
    u16* orB = po + base + (size_t)rowB * D_;
    #pragma unroll
    for (int nb = 0; nb < 8; ++nb) {
      orA[nb * 16 + fr] = f2bf(oA[nb][r]);
      orB[nb * 16 + fr] = f2bf(oB[nb][r]);
    }
  }
}

// ---------------- combine the 2 KV-splits ----------------
__global__ void attn_combine(const u16* __restrict__ po0, const u16* __restrict__ po1,
                             const float2* __restrict__ ml, u16* __restrict__ Og) {
  const int idx = blockIdx.x * blockDim.x + threadIdx.x;  // B*H*S*16
  const int d8 = (idx & 15) * 8;
  const int row = idx >> 4;            // bh*S + s
  const int bh = row >> 11, s = row & (S_ - 1);
  const float2 v0 = ml[row];
  const float2 v1 = ml[B_ * H_ * S_ + row];
  const float m = fmaxf(v0.x, v1.x);
  const float e0 = exp2f(v0.x - m), e1 = exp2f(v1.x - m);
  const float inv = 1.0f / (v0.y * e0 + v1.y * e1);
  const size_t off = (size_t)(bh >> 4) * S_ * D_ + (size_t)s * D_ + (bh & 15) * HD_ + d8;
  u16x8_t a = *(const u16x8_t*)(po0 + off);
  u16x8_t b = *(const u16x8_t*)(po1 + off);
  u16x8_t o;
  #pragma unroll
  for (int j = 0; j < 8; ++j)
    o[j] = f2bf((bf2f(a[j]) * e0 + bf2f(b[j]) * e1) * inv);
  *(u16x8_t*)(Og + off) = o;
}

// ---------------- launch ----------------
extern "C" void kernel_launch(void* const* d_in, const int* in_sizes, int n_in,
                              void* d_out, int out_size, void* d_ws, size_t ws_size,
                              hipStream_t stream) {
  const float* x  = (const float*)d_in[0];
  const float* Wq = (const float*)d_in[1];
  const float* Wk = (const float*)d_in[2];
  const float* Wv = (const float*)d_in[3];
  const float* Wo = (const float*)d_in[4];
  const int* pos  = (const int*)d_in[5];

  char* p = (char*)d_ws;
  u16* xb  = (u16*)p; p += (size_t)B_ * S_ * D_ * 2;
  u16* Wqb = (u16*)p; p += (size_t)D_ * D_ * 2;   // Wq/Wk/Wv contiguous -> packed [6144][2048]
  u16* Wkb = (u16*)p; p += (size_t)D_ * D_ * 2;
  u16* Wvb = (u16*)p; p += (size_t)D_ * D_ * 2;
  u16* Wob = (u16*)p; p += (size_t)D_ * D_ * 2;
  u16* Qb  = (u16*)p; p += (size_t)B_ * S_ * D_ * 2;
  u16* Kb  = (u16*)p; p += (size_t)B_ * S_ * D_ * 2;
  u16* Vb  = (u16*)p; p += (size_t)B_ * S_ * D_ * 2;
  float2* tab = (float2*)p; p += (size_t)S_ * 64 * sizeof(float2);
  float2* ml  = (float2*)p; p += (size_t)2 * B_ * H_ * S_ * sizeof(float2);
  // partial-O buffers reuse dead regions: xb (dead after gemm_qkv3) and
  // Wqb+Wkb (dead after gemm_qkv3; exactly B*S*D*2 bytes combined).
  u16* po0 = xb;
  u16* po1 = Wqb;
  u16* Ob  = Qb;  // combined attention output overwrites Q (attn reads Q first)

  const int nx = B_ * S_ * D_;
  const int nw = D_ * D_;
  cvt_f32_bf16<<<nx / 1024, 256, 0, stream>>>(x,  xb,  nx);
  cvt_f32_bf16<<<nw / 1024, 256, 0, stream>>>(Wq, Wqb, nw);
  cvt_f32_bf16<<<nw / 1024, 256, 0, stream>>>(Wk, Wkb, nw);
  cvt_f32_bf16<<<nw / 1024, 256, 0, stream>>>(Wv, Wvb, nw);
  cvt_f32_bf16<<<nw / 1024, 256, 0, stream>>>(Wo, Wob, nw);
  rope_table<<<(S_ * 64) / 256, 256, 0, stream>>>(pos, tab);

  // fused QKV projection: one dispatch, N=6144 over packed weights (round-5 proven)
  gemm_qkv3<<<dim3(B_ * S_ / 128, 48), 256, 0, stream>>>(xb, Wqb, Qb, Kb, Vb);

  rope_apply<<<(B_ * S_ * H_ * 16) / 256, 256, 0, stream>>>(Qb, Kb, tab);

  // KV-split flash attention + combine
  attn_fwd<<<dim3(16, B_ * H_, 2), 256, 0, stream>>>(Qb, Kb, Vb, po0, po1, ml);
  attn_combine<<<(B_ * H_ * S_ * 16) / 256, 256, 0, stream>>>(po0, po1, ml, Ob);

  gemm_bt<true><<<dim3(B_ * S_ / 128, D_ / 128), 256, 0, stream>>>(Ob, Wob, (float*)d_out, B_ * S_, D_, D_);
}

// Round 9
// 339.721 us; speedup vs baseline: 1.0915x; 1.0915x over previous
//
#include <hip/hip_runtime.h>
#include <math.h>

// Problem constants
#define B_  2
#define S_  2048
#define D_  2048
#define H_  16
#define HD_ 128

using u16 = unsigned short;
using u32 = unsigned int;
typedef __attribute__((ext_vector_type(4))) float f32x4;
typedef __attribute__((ext_vector_type(8))) short bf16x8;   // 8 bf16 = 4 VGPRs (MFMA A/B frag)
using u16x4_t = __attribute__((ext_vector_type(4))) unsigned short;
using u16x8_t = __attribute__((ext_vector_type(8))) unsigned short;
typedef __attribute__((ext_vector_type(2))) u32 u32x2;
typedef __attribute__((ext_vector_type(4))) u32 u32x4;

__device__ __forceinline__ u16 f2bf(float f) {
  u32 u = __builtin_bit_cast(u32, f);
  u32 r = u + 0x7fffu + ((u >> 16) & 1u);   // RNE
  return (u16)(r >> 16);
}
__device__ __forceinline__ float bf2f(u16 x) {
  u32 u = ((u32)x) << 16;
  return __builtin_bit_cast(float, u);
}
// async global->LDS, 16B per lane; LDS dest = wave-uniform base + lane*16;
// global source address is PER-LANE (enables source-side swizzling).
__device__ __forceinline__ void async_copy16(const u16* g, u16* l) {
  __builtin_amdgcn_global_load_lds((const __attribute__((address_space(1))) u32*)g,
                                   (__attribute__((address_space(3))) u32*)l, 16, 0, 0);
}

// ---------------- fp32 -> bf16 convert ----------------
__global__ void cvt_f32_bf16(const float* __restrict__ src, u16* __restrict__ dst, int n) {
  int i = (blockIdx.x * blockDim.x + threadIdx.x) * 4;
  if (i >= n) return;
  float4 v = *(const float4*)(src + i);
  u16x4_t o;
  o[0] = f2bf(v.x); o[1] = f2bf(v.y); o[2] = f2bf(v.z); o[3] = f2bf(v.w);
  *(u16x4_t*)(dst + i) = o;
}

// ---------------- RoPE cos/sin table ----------------
__global__ void rope_table(const int* __restrict__ pos, float2* __restrict__ tab) {
  int t = blockIdx.x * blockDim.x + threadIdx.x;  // S*64
  if (t >= S_ * 64) return;
  int s = t >> 6, i = t & 63;
  float freq = expf(-(float)i * (9.210340371976184f / 64.0f));  // theta^{-i/64}
  float ang = (float)pos[s] * freq;
  tab[t] = make_float2(cosf(ang), sinf(ang));
}

// ---------------- RoPE apply (in-place, Q and K) ----------------
__global__ void rope_apply(u16* __restrict__ Q, u16* __restrict__ K,
                           const float2* __restrict__ tab) {
  int t = blockIdx.x * blockDim.x + threadIdx.x;  // B*S*H*16
  int g = t & 15;
  int bsh = t >> 4;
  int h = bsh & (H_ - 1);
  int bs = bsh >> 4;            // b*S + s
  int s = bs & (S_ - 1);
  size_t base = (size_t)bs * D_ + (size_t)h * HD_;
  int d2 = g * 4;
  const float2* tb = &tab[s * 64 + d2];
  float2 cs[4];
  #pragma unroll
  for (int j = 0; j < 4; ++j) cs[j] = tb[j];
  #pragma unroll
  for (int which = 0; which < 2; ++which) {
    u16* P = which ? K : Q;
    u16x4_t a = *(u16x4_t*)(P + base + d2);
    u16x4_t c = *(u16x4_t*)(P + base + 64 + d2);
    u16x4_t ra, rc;
    #pragma unroll
    for (int j = 0; j < 4; ++j) {
      float t1 = bf2f(a[j]), t2 = bf2f(c[j]);
      ra[j] = f2bf(t1 * cs[j].x - t2 * cs[j].y);
      rc[j] = f2bf(t1 * cs[j].y + t2 * cs[j].x);
    }
    *(u16x4_t*)(P + base + d2) = ra;
    *(u16x4_t*)(P + base + 64 + d2) = rc;
  }
}

// ---------------- GEMM: C = A(MxK) * Bt(NxK)^T, bf16 in, fp32 acc ----------------
// m97 structure: 128x128 tile, BK=32, 4 waves x (4x4) 16x16x32 MFMA, global_load_lds staging.
template <bool F32OUT>
__global__ void gemm_bt(const u16* __restrict__ A, const u16* __restrict__ Bt,
                        void* __restrict__ Cout, int M, int N, int K) {
  __shared__ u16 lA[128 * 32];
  __shared__ u16 lB[128 * 32];
  const int tid = threadIdx.x;
  const int lane = tid & 63;
  const int w = tid >> 6;            // wave 0..3
  const int wr = w >> 1, wc = w & 1; // 2x2 waves of 64x64
  const int bm = blockIdx.x * 128;
  const int bn = blockIdx.y * 128;
  const int fr = lane & 15, fq = lane >> 4;
  f32x4 acc[4][4] = {};
  for (int k0 = 0; k0 < K; k0 += 32) {
    // stage: 8 chunks of 1KB per matrix; wave w does chunks {w, w+4}
    #pragma unroll
    for (int c = w; c < 8; c += 4) {
      const int e = c * 512 + lane * 8;       // element offset in [128][32] tile
      const int r = e >> 5, col = e & 31;
      async_copy16(A + (size_t)(bm + r) * K + k0 + col, lA + c * 512);
      async_copy16(Bt + (size_t)(bn + r) * K + k0 + col, lB + c * 512);
    }
    __syncthreads();   // drains vmcnt
    bf16x8 af[4], bfr[4];
    #pragma unroll
    for (int i = 0; i < 4; ++i) {
      af[i]  = *(const bf16x8*)&lA[(wr * 64 + i * 16 + fr) * 32 + fq * 8];
      bfr[i] = *(const bf16x8*)&lB[(wc * 64 + i * 16 + fr) * 32 + fq * 8];
    }
    #pragma unroll
    for (int i = 0; i < 4; ++i)
      #pragma unroll
      for (int j = 0; j < 4; ++j)
        acc[i][j] = __builtin_amdgcn_mfma_f32_16x16x32_bf16(af[i], bfr[j], acc[i][j], 0, 0, 0);
    __syncthreads();
  }
  // C/D layout: col = lane&15, row = (lane>>4)*4 + reg  [m89/m91 verified]
  #pragma unroll
  for (int i = 0; i < 4; ++i)
    #pragma unroll
    for (int j = 0; j < 4; ++j) {
      const int row = bm + wr * 64 + i * 16 + fq * 4;
      const int col = bn + wc * 64 + j * 16 + fr;
      #pragma unroll
      for (int r = 0; r < 4; ++r) {
        const float v = acc[i][j][r];
        if (F32OUT) ((float*)Cout)[(size_t)(row + r) * N + col] = v;
        else        ((u16*)Cout)[(size_t)(row + r) * N + col] = f2bf(v);
      }
    }
}

// ---------------- fused QKV GEMM: Bt is packed [6144][2048] (Wq;Wk;Wv) ----------------
// Same m97 structure; output routed to Q/K/V by bn>>11. 1536 blocks = 6/CU. (round-5 proven)
__global__ void gemm_qkv3(const u16* __restrict__ A, const u16* __restrict__ Bt,
                          u16* __restrict__ Qo, u16* __restrict__ Ko, u16* __restrict__ Vo) {
  __shared__ u16 lA[128 * 32];
  __shared__ u16 lB[128 * 32];
  const int tid = threadIdx.x;
  const int lane = tid & 63;
  const int w = tid >> 6;
  const int wr = w >> 1, wc = w & 1;
  const int bm = blockIdx.x * 128;
  const int bn = blockIdx.y * 128;          // 0..6016
  const int fr = lane & 15, fq = lane >> 4;
  const int K = D_;
  f32x4 acc[4][4] = {};
  for (int k0 = 0; k0 < K; k0 += 32) {
    #pragma unroll
    for (int c = w; c < 8; c += 4) {
      const int e = c * 512 + lane * 8;
      const int r = e >> 5, col = e & 31;
      async_copy16(A + (size_t)(bm + r) * K + k0 + col, lA + c * 512);
      async_copy16(Bt + (size_t)(bn + r) * K + k0 + col, lB + c * 512);
    }
    __syncthreads();
    bf16x8 af[4], bfr[4];
    #pragma unroll
    for (int i = 0; i < 4; ++i) {
      af[i]  = *(const bf16x8*)&lA[(wr * 64 + i * 16 + fr) * 32 + fq * 8];
      bfr[i] = *(const bf16x8*)&lB[(wc * 64 + i * 16 + fr) * 32 + fq * 8];
    }
    #pragma unroll
    for (int i = 0; i < 4; ++i)
      #pragma unroll
      for (int j = 0; j < 4; ++j)
        acc[i][j] = __builtin_amdgcn_mfma_f32_16x16x32_bf16(af[i], bfr[j], acc[i][j], 0, 0, 0);
    __syncthreads();
  }
  u16* out = (bn < 2048) ? Qo : (bn < 4096) ? Ko : Vo;
  const int bnl = bn & 2047;
  #pragma unroll
  for (int i = 0; i < 4; ++i)
    #pragma unroll
    for (int j = 0; j < 4; ++j) {
      const int row = bm + wr * 64 + i * 16 + fq * 4;
      const int col = bnl + wc * 64 + j * 16 + fr;
      #pragma unroll
      for (int r = 0; r < 4; ++r)
        out[(size_t)(row + r) * D_ + col] = f2bf(acc[i][j][r]);
    }
}

// ---------------- causal flash attention, KV-split + swapped-QK softmax ----------------
// grid: (16, B*H, 2). Block (x, bh, split): q-tiles {x, 31-x}, balanced KV ranges.
// Round-9: QK^T computed SWAPPED: mfma(K_frag, Q_frag) -> D[col=q (lane&15),
// row=kv (fq*4+reg)]. Each lane owns 8 scores of ONE q-row -> softmax row-reduce
// is 7 register fmax + TWO shfl_xor (d=16,32) instead of 4x 4-step shfl chains
// (shfl = LDS-pipe op, ~50cy dep latency; the old chains were the critical path).
// m/l are per-lane scalars; O-rescale gets al via 4 independent shfl broadcasts.
// A/B frag layouts are identical for this MFMA family (proven in-kernel: Q loads
// with the same pattern as K), so the swap is pure operand reordering.
// Staging/pipeline identical to round 8 (dbuf, 1 barrier/tile, DMA'd swizzled K).
#define QB 64
#define KB 32
#define PLD 36    // P row stride (72B): [q][kv] layout; b64 reads aligned

__global__ __launch_bounds__(256, 2)
void attn_fwd(const u16* __restrict__ Qg, const u16* __restrict__ Kg,
              const u16* __restrict__ Vg, u16* __restrict__ po0,
              u16* __restrict__ po1, float2* __restrict__ ml) {
  __shared__ u16 lK[2][KB * HD_];   // linear [kv][hd], source-swizzled content
  __shared__ u16 lV[2][HD_ * 40];   // swizzled V^T
  __shared__ u16 lP[4][16 * PLD];   // per-wave P 16x32, [q][kv]
  const int tid = threadIdx.x;
  const int lane = tid & 63;
  const int w = tid >> 6;
  const int fr = lane & 15, fq = lane >> 4;
  const int bh = blockIdx.y;
  const int split = blockIdx.z;
  const size_t base = (size_t)(bh >> 4) * S_ * D_ + (size_t)(bh & 15) * HD_;
  const int xA = blockIdx.x;                 // 0..15
  const int qA = xA * QB, qB = (31 - xA) * QB;
  const int ntA = (qA + QB) / KB;            // 2..32
  const int ntB = (qB + QB) / KB;            // 34..64
  const int c = (ntA <= 16) ? (33 - ntA) : 16;   // balanced split point
  const int t0 = split ? c : 0;
  const int t1 = split ? ntB : c;
  const float kscale = 0.08838834764831843f * 1.4426950408889634f; // 1/sqrt(128)*log2e

  // Q fragments for both q-tiles (row=lane&15 -> q, k=(lane>>4)*8+j -> hd)
  bf16x8 qfA[4], qfB[4];
  {
    const u16* qpa = Qg + base + (size_t)(qA + w * 16 + fr) * D_ + fq * 8;
    const u16* qpb = Qg + base + (size_t)(qB + w * 16 + fr) * D_ + fq * 8;
    #pragma unroll
    for (int kk = 0; kk < 4; ++kk) {
      qfA[kk] = *(const bf16x8*)(qpa + kk * 32);
      qfB[kk] = *(const bf16x8*)(qpb + kk * 32);
    }
  }
  f32x4 oA[8] = {}, oB[8] = {};
  float mAs = -INFINITY, lAs = 0.f, mBs = -INFINITY, lBs = 0.f;

  // K staging: wave w issues DMA chunks {w, w+4}; chunk c covers rows 4c..4c+3.
  // Lane -> (row = 4c + lane>>4, slot16 = lane&15); source col-slot = slot ^ (row&7).
  auto stageK = [&](int buf, int kv0) {
    #pragma unroll
    for (int cc = w; cc < 8; cc += 4) {
      const int row = cc * 4 + (lane >> 4);
      const int slot = (lane & 15) ^ (row & 7);
      async_copy16(Kg + base + (size_t)(kv0 + row) * D_ + slot * 8, &lK[buf][cc * 512]);
    }
  };
  // V staging: thread -> (kv row = tid>>3, 16 hd at (tid&7)*16)
  const int srow = tid >> 3, sc0 = (tid & 7) * 16;
  const u32 swz = (u32)((sc0 >> 4) & 7) << 4;
  const u32 rb = (u32)srow * 2;
  u16x8_t rv0, rv1;
  auto loadV = [&](int kv0) {
    const u16* gv = Vg + base + (size_t)(kv0 + srow) * D_ + sc0;
    rv0 = *(const u16x8_t*)gv; rv1 = *(const u16x8_t*)(gv + 8);
  };
  auto writeV = [&](int buf) {
    char* lv = (char*)&lV[buf][0];
    #pragma unroll
    for (int j = 0; j < 8; ++j) {
      *(u16*)(lv + ((((u32)(sc0 + j) * 80) + rb) ^ swz))     = rv0[j];
      *(u16*)(lv + ((((u32)(sc0 + 8 + j) * 80) + rb) ^ swz)) = rv1[j];
    }
  };

  // swapped-layout softmax: lane owns q=fr's row, kv slots fq*4+r (+16c)
  auto softmax_sw = [&](const f32x4& s0, const f32x4& s1, float& mrow, float& lrow,
                        f32x4* o, int q0t, int kv0) {
    const int qg = q0t + w * 16 + fr;
    const bool notfull = (kv0 + KB - 1 > q0t);
    float v[8];
    #pragma unroll
    for (int r = 0; r < 4; ++r) {
      v[r]     = s0[r] * kscale;
      v[4 + r] = s1[r] * kscale;
      if (notfull) {
        if (kv0 + fq * 4 + r > qg)      v[r]     = -INFINITY;
        if (kv0 + 16 + fq * 4 + r > qg) v[4 + r] = -INFINITY;
      }
    }
    float mx = fmaxf(fmaxf(fmaxf(v[0], v[1]), fmaxf(v[2], v[3])),
                     fmaxf(fmaxf(v[4], v[5]), fmaxf(v[6], v[7])));
    mx = fmaxf(mx, __shfl_xor(mx, 16));
    mx = fmaxf(mx, __shfl_xor(mx, 32));
    const float mn = fmaxf(mrow, mx);
    const float al = exp2f(mrow - mn);
    mrow = mn;
    float p[8];
    #pragma unroll
    for (int j = 0; j < 8; ++j) p[j] = exp2f(v[j] - mn);
    float rs = ((p[0] + p[1]) + (p[2] + p[3])) + ((p[4] + p[5]) + (p[6] + p[7]));
    rs += __shfl_xor(rs, 16);
    rs += __shfl_xor(rs, 32);
    lrow = lrow * al + rs;
    #pragma unroll
    for (int r = 0; r < 4; ++r) {
      lP[w][fr * PLD + fq * 4 + r]      = f2bf(p[r]);
      lP[w][fr * PLD + 16 + fq * 4 + r] = f2bf(p[4 + r]);
    }
    // broadcast al to the lanes holding O rows q=fq*4+r (independent shfls)
    #pragma unroll
    for (int r = 0; r < 4; ++r) {
      const float ab = __shfl(al, fq * 4 + r);
      #pragma unroll
      for (int nb = 0; nb < 8; ++nb) o[nb][r] *= ab;
    }
  };

  auto pv = [&](f32x4* o, const bf16x8* vf) {
    u32x2 pa0 = *(const u32x2*)&lP[w][fr * PLD + fq * 8];
    u32x2 pa1 = *(const u32x2*)&lP[w][fr * PLD + fq * 8 + 4];
    u32x4 pc; pc[0] = pa0[0]; pc[1] = pa0[1]; pc[2] = pa1[0]; pc[3] = pa1[1];
    const bf16x8 pa = __builtin_bit_cast(bf16x8, pc);
    #pragma unroll
    for (int nb = 0; nb < 8; ++nb)
      o[nb] = __builtin_amdgcn_mfma_f32_16x16x32_bf16(pa, vf[nb], o[nb], 0, 0, 0);
  };

  // prologue: stage tile t0 into buffer 0
  stageK(0, t0 * KB);
  loadV(t0 * KB);
  writeV(0);

  for (int t = t0; t < t1; ++t) {
    const int kv0 = t * KB;
    const int cur = (t - t0) & 1, nxt = cur ^ 1;
    __syncthreads();   // drains vmcnt/lgkmcnt: lK[cur] DMA + lV[cur] writes visible
    if (t + 1 < t1) {
      stageK(nxt, kv0 + KB);   // async DMA, drained by next barrier
      loadV(kv0 + KB);         // regs; consumed by writeV after compute
    }

    const bool doA = (t < ntA);
    // SWAPPED QK^T: mfma(K, Q) -> lane owns one q-row's scores
    f32x4 sA0 = {}, sA1 = {}, sB0 = {}, sB1 = {};
    #pragma unroll
    for (int kk = 0; kk < 4; ++kk) {
      const int sl = ((kk * 4 + fq) ^ (fr & 7)) * 16;
      bf16x8 k0f = *(const bf16x8*)((const char*)&lK[cur][0] + fr * 256 + sl);
      bf16x8 k1f = *(const bf16x8*)((const char*)&lK[cur][0] + (16 + fr) * 256 + sl);
      if (doA) {
        sA0 = __builtin_amdgcn_mfma_f32_16x16x32_bf16(k0f, qfA[kk], sA0, 0, 0, 0);
        sA1 = __builtin_amdgcn_mfma_f32_16x16x32_bf16(k1f, qfA[kk], sA1, 0, 0, 0);
      }
      sB0 = __builtin_amdgcn_mfma_f32_16x16x32_bf16(k0f, qfB[kk], sB0, 0, 0, 0);
      sB1 = __builtin_amdgcn_mfma_f32_16x16x32_bf16(k1f, qfB[kk], sB1, 0, 0, 0);
    }

    // V fragments (shared by both q-tiles): b128 reads, wave-uniform XOR term
    bf16x8 vf[8];
    #pragma unroll
    for (int nb = 0; nb < 8; ++nb) {
      const u32 off = (((u32)(nb * 16 + fr) * 80) + (u32)fq * 16) ^ ((u32)nb << 4);
      vf[nb] = *(const bf16x8*)((const char*)&lV[cur][0] + off);
    }

    if (doA) { softmax_sw(sA0, sA1, mAs, lAs, oA, qA, kv0); pv(oA, vf); }
    softmax_sw(sB0, sB1, mBs, lBs, oB, qB, kv0);
    pv(oB, vf);

    if (t + 1 < t1) writeV(nxt);   // after compute
  }

  // epilogue: write UNNORMALIZED partials + (m,l) per row
  u16* po = split ? po1 : po0;
  float2* mlp = ml + (size_t)split * (B_ * H_ * S_) + (size_t)bh * S_;
  if (lane < 16) {   // fq==0 lanes hold q=fr's (m,l) (uniform across fq after butterfly)
    mlp[qA + w * 16 + fr] = make_float2(mAs, lAs);
    mlp[qB + w * 16 + fr] = make_float2(mBs, lBs);
  }
  #pragma unroll
  for (int r = 0; r < 4; ++r) {
    const int rowA = qA + w * 16 + fq * 4 + r;
    const int rowB = qB + w * 16 + fq * 4 + r;
    u16* orA = po + base + (size_t)rowA * D_;
    u16* orB = po + base + (size_t)rowB * D_;
    #pragma unroll
    for (int nb = 0; nb < 8; ++nb) {
      orA[nb * 16 + fr] = f2bf(oA[nb][r]);
      orB[nb * 16 + fr] = f2bf(oB[nb][r]);
    }
  }
}

// ---------------- combine the 2 KV-splits ----------------
__global__ void attn_combine(const u16* __restrict__ po0, const u16* __restrict__ po1,
                             const float2* __restrict__ ml, u16* __restrict__ Og) {
  const int idx = blockIdx.x * blockDim.x + threadIdx.x;  // B*H*S*16
  const int d8 = (idx & 15) * 8;
  const int row = idx >> 4;            // bh*S + s
  const int bh = row >> 11, s = row & (S_ - 1);
  const float2 v0 = ml[row];
  const float2 v1 = ml[B_ * H_ * S_ + row];
  const float m = fmaxf(v0.x, v1.x);
  const float e0 = exp2f(v0.x - m), e1 = exp2f(v1.x - m);
  const float inv = 1.0f / (v0.y * e0 + v1.y * e1);
  const size_t off = (size_t)(bh >> 4) * S_ * D_ + (size_t)s * D_ + (bh & 15) * HD_ + d8;
  u16x8_t a = *(const u16x8_t*)(po0 + off);
  u16x8_t b = *(const u16x8_t*)(po1 + off);
  u16x8_t o;
  #pragma unroll
  for (int j = 0; j < 8; ++j)
    o[j] = f2bf((bf2f(a[j]) * e0 + bf2f(b[j]) * e1) * inv);
  *(u16x8_t*)(Og + off) = o;
}

// ---------------- launch ----------------
extern "C" void kernel_launch(void* const* d_in, const int* in_sizes, int n_in,
                              void* d_out, int out_size, void* d_ws, size_t ws_size,
                              hipStream_t stream) {
  const float* x  = (const float*)d_in[0];
  const float* Wq = (const float*)d_in[1];
  const float* Wk = (const float*)d_in[2];
  const float* Wv = (const float*)d_in[3];
  const float* Wo = (const float*)d_in[4];
  const int* pos  = (const int*)d_in[5];

  char* p = (char*)d_ws;
  u16* xb  = (u16*)p; p += (size_t)B_ * S_ * D_ * 2;
  u16* Wqb = (u16*)p; p += (size_t)D_ * D_ * 2;   // Wq/Wk/Wv contiguous -> packed [6144][2048]
  u16* Wkb = (u16*)p; p += (size_t)D_ * D_ * 2;
  u16* Wvb = (u16*)p; p += (size_t)D_ * D_ * 2;
  u16* Wob = (u16*)p; p += (size_t)D_ * D_ * 2;
  u16* Qb  = (u16*)p; p += (size_t)B_ * S_ * D_ * 2;
  u16* Kb  = (u16*)p; p += (size_t)B_ * S_ * D_ * 2;
  u16* Vb  = (u16*)p; p += (size_t)B_ * S_ * D_ * 2;
  float2* tab = (float2*)p; p += (size_t)S_ * 64 * sizeof(float2);
  float2* ml  = (float2*)p; p += (size_t)2 * B_ * H_ * S_ * sizeof(float2);
  // partial-O buffers reuse dead regions: xb (dead after gemm_qkv3) and
  // Wqb+Wkb (dead after gemm_qkv3; exactly B*S*D*2 bytes combined).
  u16* po0 = xb;
  u16* po1 = Wqb;
  u16* Ob  = Qb;  // combined attention output overwrites Q (attn reads Q first)

  const int nx = B_ * S_ * D_;
  const int nw = D_ * D_;
  cvt_f32_bf16<<<nx / 1024, 256, 0, stream>>>(x,  xb,  nx);
  cvt_f32_bf16<<<nw / 1024, 256, 0, stream>>>(Wq, Wqb, nw);
  cvt_f32_bf16<<<nw / 1024, 256, 0, stream>>>(Wk, Wkb, nw);
  cvt_f32_bf16<<<nw / 1024, 256, 0, stream>>>(Wv, Wvb, nw);
  cvt_f32_bf16<<<nw / 1024, 256, 0, stream>>>(Wo, Wob, nw);
  rope_table<<<(S_ * 64) / 256, 256, 0, stream>>>(pos, tab);

  // fused QKV projection: one dispatch, N=6144 over packed weights (round-5 proven)
  gemm_qkv3<<<dim3(B_ * S_ / 128, 48), 256, 0, stream>>>(xb, Wqb, Qb, Kb, Vb);

  rope_apply<<<(B_ * S_ * H_ * 16) / 256, 256, 0, stream>>>(Qb, Kb, tab);

  // KV-split flash attention + combine
  attn_fwd<<<dim3(16, B_ * H_, 2), 256, 0, stream>>>(Qb, Kb, Vb, po0, po1, ml);
  attn_combine<<<(B_ * H_ * S_ * 16) / 256, 256, 0, stream>>>(po0, po1, ml, Ob);

  gemm_bt<true><<<dim3(B_ * S_ / 128, D_ / 128), 256, 0, stream>>>(Ob, Wob, (float*)d_out, B_ * S_, D_, D_);
}

// Round 11
// 328.039 us; speedup vs baseline: 1.1304x; 1.0356x over previous
//
#include <hip/hip_runtime.h>
#include <math.h>

// Problem constants
#define B_  2
#define S_  2048
#define D_  2048
#define H_  16
#define HD_ 128

using u16 = unsigned short;
using u32 = unsigned int;
typedef __attribute__((ext_vector_type(4))) float f32x4;
typedef __attribute__((ext_vector_type(8))) short bf16x8;   // 8 bf16 = 4 VGPRs (MFMA A/B frag)
using u16x4_t = __attribute__((ext_vector_type(4))) unsigned short;
using u16x8_t = __attribute__((ext_vector_type(8))) unsigned short;
typedef __attribute__((ext_vector_type(2))) u32 u32x2;
typedef __attribute__((ext_vector_type(4))) u32 u32x4;

__device__ __forceinline__ u16 f2bf(float f) {
  u32 u = __builtin_bit_cast(u32, f);
  u32 r = u + 0x7fffu + ((u >> 16) & 1u);   // RNE
  return (u16)(r >> 16);
}
__device__ __forceinline__ float bf2f(u16 x) {
  u32 u = ((u32)x) << 16;
  return __builtin_bit_cast(float, u);
}
// async global->LDS, 16B per lane; LDS dest = wave-uniform base + lane*16;
// global source address is PER-LANE (enables source-side swizzling).
__device__ __forceinline__ void async_copy16(const u16* g, u16* l) {
  __builtin_amdgcn_global_load_lds((const __attribute__((address_space(1))) u32*)g,
                                   (__attribute__((address_space(3))) u32*)l, 16, 0, 0);
}

// ---------------- fp32 -> bf16 convert ----------------
__global__ void cvt_f32_bf16(const float* __restrict__ src, u16* __restrict__ dst, int n) {
  int i = (blockIdx.x * blockDim.x + threadIdx.x) * 4;
  if (i >= n) return;
  float4 v = *(const float4*)(src + i);
  u16x4_t o;
  o[0] = f2bf(v.x); o[1] = f2bf(v.y); o[2] = f2bf(v.z); o[3] = f2bf(v.w);
  *(u16x4_t*)(dst + i) = o;
}

// ---------------- RoPE cos/sin table ----------------
__global__ void rope_table(const int* __restrict__ pos, float2* __restrict__ tab) {
  int t = blockIdx.x * blockDim.x + threadIdx.x;  // S*64
  if (t >= S_ * 64) return;
  int s = t >> 6, i = t & 63;
  float freq = expf(-(float)i * (9.210340371976184f / 64.0f));  // theta^{-i/64}
  float ang = (float)pos[s] * freq;
  tab[t] = make_float2(cosf(ang), sinf(ang));
}

// ---------------- RoPE apply (in-place, Q and K) ----------------
__global__ void rope_apply(u16* __restrict__ Q, u16* __restrict__ K,
                           const float2* __restrict__ tab) {
  int t = blockIdx.x * blockDim.x + threadIdx.x;  // B*S*H*16
  int g = t & 15;
  int bsh = t >> 4;
  int h = bsh & (H_ - 1);
  int bs = bsh >> 4;            // b*S + s
  int s = bs & (S_ - 1);
  size_t base = (size_t)bs * D_ + (size_t)h * HD_;
  int d2 = g * 4;
  const float2* tb = &tab[s * 64 + d2];
  float2 cs[4];
  #pragma unroll
  for (int j = 0; j < 4; ++j) cs[j] = tb[j];
  #pragma unroll
  for (int which = 0; which < 2; ++which) {
    u16* P = which ? K : Q;
    u16x4_t a = *(u16x4_t*)(P + base + d2);
    u16x4_t c = *(u16x4_t*)(P + base + 64 + d2);
    u16x4_t ra, rc;
    #pragma unroll
    for (int j = 0; j < 4; ++j) {
      float t1 = bf2f(a[j]), t2 = bf2f(c[j]);
      ra[j] = f2bf(t1 * cs[j].x - t2 * cs[j].y);
      rc[j] = f2bf(t1 * cs[j].y + t2 * cs[j].x);
    }
    *(u16x4_t*)(P + base + d2) = ra;
    *(u16x4_t*)(P + base + 64 + d2) = rc;
  }
}

// ---------------- GEMM: C = A(MxK) * Bt(NxK)^T, bf16 in, fp32 acc ----------------
// Round-10 structure: 128x128 tile, BK=32, TRIPLE-buffered LDS, ONE raw s_barrier
// per K-step with COUNTED vmcnt(4) (T4): tile kt+2's 4 DMA loads stay in flight
// across the barrier; no full drain. Race-free: reads of buf (kt+2)%3 ended at
// barrier kt-1 (one full barrier before the stage), wave skew <= 1 barrier.
// LDS slot swizzle (both sides, rule #21): DMA source col-slot = s ^ ((r>>1)&3)
// (linear dest), read col = fq ^ ((row>>1)&3). Per sequential 8-lane phase the
// spans (fr&1, fq^((fr>>1)&3)) are 8 DISTINCT 16B groups = all 32 banks once
// (old layout: 4 lanes per span within a phase -> the 1.26e7 conflicts).
template <bool F32OUT>
__global__ void gemm_bt(const u16* __restrict__ A, const u16* __restrict__ Bt,
                        void* __restrict__ Cout, int M, int N, int K) {
  __shared__ u16 lA[3][128 * 32];
  __shared__ u16 lB[3][128 * 32];
  const int tid = threadIdx.x;
  const int lane = tid & 63;
  const int w = tid >> 6;            // wave 0..3
  const int wr = w >> 1, wc = w & 1; // 2x2 waves of 64x64
  const int bm = blockIdx.x * 128;
  const int bn = blockIdx.y * 128;
  const int fr = lane & 15, fq = lane >> 4;
  const int KT = K >> 5;
  f32x4 acc[4][4] = {};

  auto stage = [&](int buf, int kt) {
    const int k0 = kt << 5;
    #pragma unroll
    for (int c = w; c < 8; c += 4) {
      const int r = c * 16 + (lane >> 2);
      const int col = ((lane & 3) ^ ((r >> 1) & 3)) * 8;   // pre-swizzled source slot
      async_copy16(A + (size_t)(bm + r) * K + k0 + col, &lA[buf][c * 512]);
      async_copy16(Bt + (size_t)(bn + r) * K + k0 + col, &lB[buf][c * 512]);
    }
  };

  stage(0, 0);
  stage(1, 1);
  asm volatile("s_waitcnt vmcnt(4)" ::: "memory");   // tile 0 landed; tile 1 in flight
  __builtin_amdgcn_s_barrier();
  asm volatile("" ::: "memory");

  int p = 0, sb = 2;
  #pragma unroll 1
  for (int kt = 0; kt < KT; ++kt) {
    if (kt + 2 < KT) stage(sb, kt + 2);
    bf16x8 af[4], bfr[4];
    #pragma unroll
    for (int i = 0; i < 4; ++i) {
      const int ra = wr * 64 + i * 16 + fr;
      const int rb = wc * 64 + i * 16 + fr;
      af[i]  = *(const bf16x8*)&lA[p][ra * 32 + ((fq ^ ((ra >> 1) & 3)) * 8)];
      bfr[i] = *(const bf16x8*)&lB[p][rb * 32 + ((fq ^ ((rb >> 1) & 3)) * 8)];
    }
    #pragma unroll
    for (int i = 0; i < 4; ++i)
      #pragma unroll
      for (int j = 0; j < 4; ++j)
        acc[i][j] = __builtin_amdgcn_mfma_f32_16x16x32_bf16(af[i], bfr[j], acc[i][j], 0, 0, 0);
    if (kt + 1 < KT) {
      if (kt + 2 < KT) asm volatile("s_waitcnt vmcnt(4)" ::: "memory");  // kt+1 landed
      else             asm volatile("s_waitcnt vmcnt(0)" ::: "memory");  // tail drain
      __builtin_amdgcn_s_barrier();
      asm volatile("" ::: "memory");
    }
    p  = (p == 2) ? 0 : p + 1;
    sb = (sb == 2) ? 0 : sb + 1;
  }
  // C/D layout: col = lane&15, row = (lane>>4)*4 + reg  [m89/m91 verified]
  #pragma unroll
  for (int i = 0; i < 4; ++i)
    #pragma unroll
    for (int j = 0; j < 4; ++j) {
      const int row = bm + wr * 64 + i * 16 + fq * 4;
      const int col = bn + wc * 64 + j * 16 + fr;
      #pragma unroll
      for (int r = 0; r < 4; ++r) {
        const float v = acc[i][j][r];
        if (F32OUT) ((float*)Cout)[(size_t)(row + r) * N + col] = v;
        else        ((u16*)Cout)[(size_t)(row + r) * N + col] = f2bf(v);
      }
    }
}

// ---------------- fused QKV GEMM: Bt is packed [6144][2048] (Wq;Wk;Wv) ----------------
// Same round-10 pipelined body; output routed to Q/K/V by bn>>11. 1536 blocks.
__global__ void gemm_qkv3(const u16* __restrict__ A, const u16* __restrict__ Bt,
                          u16* __restrict__ Qo, u16* __restrict__ Ko, u16* __restrict__ Vo) {
  __shared__ u16 lA[3][128 * 32];
  __shared__ u16 lB[3][128 * 32];
  const int tid = threadIdx.x;
  const int lane = tid & 63;
  const int w = tid >> 6;
  const int wr = w >> 1, wc = w & 1;
  const int bm = blockIdx.x * 128;
  const int bn = blockIdx.y * 128;          // 0..6016
  const int fr = lane & 15, fq = lane >> 4;
  const int K = D_;
  const int KT = K >> 5;                    // 64
  f32x4 acc[4][4] = {};

  auto stage = [&](int buf, int kt) {
    const int k0 = kt << 5;
    #pragma unroll
    for (int c = w; c < 8; c += 4) {
      const int r = c * 16 + (lane >> 2);
      const int col = ((lane & 3) ^ ((r >> 1) & 3)) * 8;
      async_copy16(A + (size_t)(bm + r) * K + k0 + col, &lA[buf][c * 512]);
      async_copy16(Bt + (size_t)(bn + r) * K + k0 + col, &lB[buf][c * 512]);
    }
  };

  stage(0, 0);
  stage(1, 1);
  asm volatile("s_waitcnt vmcnt(4)" ::: "memory");
  __builtin_amdgcn_s_barrier();
  asm volatile("" ::: "memory");

  int p = 0, sb = 2;
  #pragma unroll 1
  for (int kt = 0; kt < KT; ++kt) {
    if (kt + 2 < KT) stage(sb, kt + 2);
    bf16x8 af[4], bfr[4];
    #pragma unroll
    for (int i = 0; i < 4; ++i) {
      const int ra = wr * 64 + i * 16 + fr;
      const int rb = wc * 64 + i * 16 + fr;
      af[i]  = *(const bf16x8*)&lA[p][ra * 32 + ((fq ^ ((ra >> 1) & 3)) * 8)];
      bfr[i] = *(const bf16x8*)&lB[p][rb * 32 + ((fq ^ ((rb >> 1) & 3)) * 8)];
    }
    #pragma unroll
    for (int i = 0; i < 4; ++i)
      #pragma unroll
      for (int j = 0; j < 4; ++j)
        acc[i][j] = __builtin_amdgcn_mfma_f32_16x16x32_bf16(af[i], bfr[j], acc[i][j], 0, 0, 0);
    if (kt + 1 < KT) {
      if (kt + 2 < KT) asm volatile("s_waitcnt vmcnt(4)" ::: "memory");
      else             asm volatile("s_waitcnt vmcnt(0)" ::: "memory");
      __builtin_amdgcn_s_barrier();
      asm volatile("" ::: "memory");
    }
    p  = (p == 2) ? 0 : p + 1;
    sb = (sb == 2) ? 0 : sb + 1;
  }
  u16* out = (bn < 2048) ? Qo : (bn < 4096) ? Ko : Vo;
  const int bnl = bn & 2047;
  #pragma unroll
  for (int i = 0; i < 4; ++i)
    #pragma unroll
    for (int j = 0; j < 4; ++j) {
      const int row = bm + wr * 64 + i * 16 + fq * 4;
      const int col = bnl + wc * 64 + j * 16 + fr;
      #pragma unroll
      for (int r = 0; r < 4; ++r)
        out[(size_t)(row + r) * D_ + col] = f2bf(acc[i][j][r]);
    }
}

// ---------------- causal flash attention, KV-split + swapped-QK softmax ----------------
// (round-9 proven, unchanged)
#define QB 64
#define KB 32
#define PLD 36    // P row stride (72B): [q][kv] layout; b64 reads aligned

__global__ __launch_bounds__(256, 2)
void attn_fwd(const u16* __restrict__ Qg, const u16* __restrict__ Kg,
              const u16* __restrict__ Vg, u16* __restrict__ po0,
              u16* __restrict__ po1, float2* __restrict__ ml) {
  __shared__ u16 lK[2][KB * HD_];   // linear [kv][hd], source-swizzled content
  __shared__ u16 lV[2][HD_ * 40];   // swizzled V^T
  __shared__ u16 lP[4][16 * PLD];   // per-wave P 16x32, [q][kv]
  const int tid = threadIdx.x;
  const int lane = tid & 63;
  const int w = tid >> 6;
  const int fr = lane & 15, fq = lane >> 4;
  const int bh = blockIdx.y;
  const int split = blockIdx.z;
  const size_t base = (size_t)(bh >> 4) * S_ * D_ + (size_t)(bh & 15) * HD_;
  const int xA = blockIdx.x;                 // 0..15
  const int qA = xA * QB, qB = (31 - xA) * QB;
  const int ntA = (qA + QB) / KB;            // 2..32
  const int ntB = (qB + QB) / KB;            // 34..64
  const int c = (ntA <= 16) ? (33 - ntA) : 16;   // balanced split point
  const int t0 = split ? c : 0;
  const int t1 = split ? ntB : c;
  const float kscale = 0.08838834764831843f * 1.4426950408889634f; // 1/sqrt(128)*log2e

  // Q fragments for both q-tiles (row=lane&15 -> q, k=(lane>>4)*8+j -> hd)
  bf16x8 qfA[4], qfB[4];
  {
    const u16* qpa = Qg + base + (size_t)(qA + w * 16 + fr) * D_ + fq * 8;
    const u16* qpb = Qg + base + (size_t)(qB + w * 16 + fr) * D_ + fq * 8;
    #pragma unroll
    for (int kk = 0; kk < 4; ++kk) {
      qfA[kk] = *(const bf16x8*)(qpa + kk * 32);
      qfB[kk] = *(const bf16x8*)(qpb + kk * 32);
    }
  }
  f32x4 oA[8] = {}, oB[8] = {};
  float mAs = -INFINITY, lAs = 0.f, mBs = -INFINITY, lBs = 0.f;

  auto stageK = [&](int buf, int kv0) {
    #pragma unroll
    for (int cc = w; cc < 8; cc += 4) {
      const int row = cc * 4 + (lane >> 4);
      const int slot = (lane & 15) ^ (row & 7);
      async_copy16(Kg + base + (size_t)(kv0 + row) * D_ + slot * 8, &lK[buf][cc * 512]);
    }
  };
  const int srow = tid >> 3, sc0 = (tid & 7) * 16;
  const u32 swz = (u32)((sc0 >> 4) & 7) << 4;
  const u32 rb = (u32)srow * 2;
  u16x8_t rv0, rv1;
  auto loadV = [&](int kv0) {
    const u16* gv = Vg + base + (size_t)(kv0 + srow) * D_ + sc0;
    rv0 = *(const u16x8_t*)gv; rv1 = *(const u16x8_t*)(gv + 8);
  };
  auto writeV = [&](int buf) {
    char* lv = (char*)&lV[buf][0];
    #pragma unroll
    for (int j = 0; j < 8; ++j) {
      *(u16*)(lv + ((((u32)(sc0 + j) * 80) + rb) ^ swz))     = rv0[j];
      *(u16*)(lv + ((((u32)(sc0 + 8 + j) * 80) + rb) ^ swz)) = rv1[j];
    }
  };

  // swapped-layout softmax: lane owns q=fr's row, kv slots fq*4+r (+16c)
  auto softmax_sw = [&](const f32x4& s0, const f32x4& s1, float& mrow, float& lrow,
                        f32x4* o, int q0t, int kv0) {
    const int qg = q0t + w * 16 + fr;
    const bool notfull = (kv0 + KB - 1 > q0t);
    float v[8];
    #pragma unroll
    for (int r = 0; r < 4; ++r) {
      v[r]     = s0[r] * kscale;
      v[4 + r] = s1[r] * kscale;
      if (notfull) {
        if (kv0 + fq * 4 + r > qg)      v[r]     = -INFINITY;
        if (kv0 + 16 + fq * 4 + r > qg) v[4 + r] = -INFINITY;
      }
    }
    float mx = fmaxf(fmaxf(fmaxf(v[0], v[1]), fmaxf(v[2], v[3])),
                     fmaxf(fmaxf(v[4], v[5]), fmaxf(v[6], v[7])));
    mx = fmaxf(mx, __shfl_xor(mx, 16));
    mx = fmaxf(mx, __shfl_xor(mx, 32));
    const float mn = fmaxf(mrow, mx);
    const float al = exp2f(mrow - mn);
    mrow = mn;
    float p[8];
    #pragma unroll
    for (int j = 0; j < 8; ++j) p[j] = exp2f(v[j] - mn);
    float rs = ((p[0] + p[1]) + (p[2] + p[3])) + ((p[4] + p[5]) + (p[6] + p[7]));
    rs += __shfl_xor(rs, 16);
    rs += __shfl_xor(rs, 32);
    lrow = lrow * al + rs;
    #pragma unroll
    for (int r = 0; r < 4; ++r) {
      lP[w][fr * PLD + fq * 4 + r]      = f2bf(p[r]);
      lP[w][fr * PLD + 16 + fq * 4 + r] = f2bf(p[4 + r]);
    }
    #pragma unroll
    for (int r = 0; r < 4; ++r) {
      const float ab = __shfl(al, fq * 4 + r);
      #pragma unroll
      for (int nb = 0; nb < 8; ++nb) o[nb][r] *= ab;
    }
  };

  auto pv = [&](f32x4* o, const bf16x8* vf) {
    u32x2 pa0 = *(const u32x2*)&lP[w][fr * PLD + fq * 8];
    u32x2 pa1 = *(const u32x2*)&lP[w][fr * PLD + fq * 8 + 4];
    u32x4 pc; pc[0] = pa0[0]; pc[1] = pa0[1]; pc[2] = pa1[0]; pc[3] = pa1[1];
    const bf16x8 pa = __builtin_bit_cast(bf16x8, pc);
    #pragma unroll
    for (int nb = 0; nb < 8; ++nb)
      o[nb] = __builtin_amdgcn_mfma_f32_16x16x32_bf16(pa, vf[nb], o[nb], 0, 0, 0);
  };

  // prologue: stage tile t0 into buffer 0
  stageK(0, t0 * KB);
  loadV(t0 * KB);
  writeV(0);

  for (int t = t0; t < t1; ++t) {
    const int kv0 = t * KB;
    const int cur = (t - t0) & 1, nxt = cur ^ 1;
    __syncthreads();   // drains vmcnt/lgkmcnt: lK[cur] DMA + lV[cur] writes visible
    if (t + 1 < t1) {
      stageK(nxt, kv0 + KB);   // async DMA, drained by next barrier
      loadV(kv0 + KB);         // regs; consumed by writeV after compute
    }

    const bool doA = (t < ntA);
    // SWAPPED QK^T: mfma(K, Q) -> lane owns one q-row's scores
    f32x4 sA0 = {}, sA1 = {}, sB0 = {}, sB1 = {};
    #pragma unroll
    for (int kk = 0; kk < 4; ++kk) {
      const int sl = ((kk * 4 + fq) ^ (fr & 7)) * 16;
      bf16x8 k0f = *(const bf16x8*)((const char*)&lK[cur][0] + fr * 256 + sl);
      bf16x8 k1f = *(const bf16x8*)((const char*)&lK[cur][0] + (16 + fr) * 256 + sl);
      if (doA) {
        sA0 = __builtin_amdgcn_mfma_f32_16x16x32_bf16(k0f, qfA[kk], sA0, 0, 0, 0);
        sA1 = __builtin_amdgcn_mfma_f32_16x16x32_bf16(k1f, qfA[kk], sA1, 0, 0, 0);
      }
      sB0 = __builtin_amdgcn_mfma_f32_16x16x32_bf16(k0f, qfB[kk], sB0, 0, 0, 0);
      sB1 = __builtin_amdgcn_mfma_f32_16x16x32_bf16(k1f, qfB[kk], sB1, 0, 0, 0);
    }

    bf16x8 vf[8];
    #pragma unroll
    for (int nb = 0; nb < 8; ++nb) {
      const u32 off = (((u32)(nb * 16 + fr) * 80) + (u32)fq * 16) ^ ((u32)nb << 4);
      vf[nb] = *(const bf16x8*)((const char*)&lV[cur][0] + off);
    }

    if (doA) { softmax_sw(sA0, sA1, mAs, lAs, oA, qA, kv0); pv(oA, vf); }
    softmax_sw(sB0, sB1, mBs, lBs, oB, qB, kv0);
    pv(oB, vf);

    if (t + 1 < t1) writeV(nxt);   // after compute
  }

  // epilogue: write UNNORMALIZED partials + (m,l) per row
  u16* po = split ? po1 : po0;
  float2* mlp = ml + (size_t)split * (B_ * H_ * S_) + (size_t)bh * S_;
  if (lane < 16) {
    mlp[qA + w * 16 + fr] = make_float2(mAs, lAs);
    mlp[qB + w * 16 + fr] = make_float2(mBs, lBs);
  }
  #pragma unroll
  for (int r = 0; r < 4; ++r) {
    const int rowA = qA + w * 16 + fq * 4 + r;
    const int rowB = qB + w * 16 + fq * 4 + r;
    u16* orA = po + base + (size_t)rowA * D_;
    u16* orB = po + base + (size_t)rowB * D_;
    #pragma unroll
    for (int nb = 0; nb < 8; ++nb) {
      orA[nb * 16 + fr] = f2bf(oA[nb][r]);
      orB[nb * 16 + fr] = f2bf(oB[nb][r]);
    }
  }
}

// ---------------- combine the 2 KV-splits ----------------
__global__ void attn_combine(const u16* __restrict__ po0, const u16* __restrict__ po1,
                             const float2* __restrict__ ml, u16* __restrict__ Og) {
  const int idx = blockIdx.x * blockDim.x + threadIdx.x;  // B*H*S*16
  const int d8 = (idx & 15) * 8;
  const int row = idx >> 4;            // bh*S + s
  const int bh = row >> 11, s = row & (S_ - 1);
  const float2 v0 = ml[row];
  const float2 v1 = ml[B_ * H_ * S_ + row];
  const float m = fmaxf(v0.x, v1.x);
  const float e0 = exp2f(v0.x - m), e1 = exp2f(v1.x - m);
  const float inv = 1.0f / (v0.y * e0 + v1.y * e1);
  const size_t off = (size_t)(bh >> 4) * S_ * D_ + (size_t)s * D_ + (bh & 15) * HD_ + d8;
  u16x8_t a = *(const u16x8_t*)(po0 + off);
  u16x8_t b = *(const u16x8_t*)(po1 + off);
  u16x8_t o;
  #pragma unroll
  for (int j = 0; j < 8; ++j)
    o[j] = f2bf((bf2f(a[j]) * e0 + bf2f(b[j]) * e1) * inv);
  *(u16x8_t*)(Og + off) = o;
}

// ---------------- launch ----------------
extern "C" void kernel_launch(void* const* d_in, const int* in_sizes, int n_in,
                              void* d_out, int out_size, void* d_ws, size_t ws_size,
                              hipStream_t stream) {
  const float* x  = (const float*)d_in[0];
  const float* Wq = (const float*)d_in[1];
  const float* Wk = (const float*)d_in[2];
  const float* Wv = (const float*)d_in[3];
  const float* Wo = (const float*)d_in[4];
  const int* pos  = (const int*)d_in[5];

  char* p = (char*)d_ws;
  u16* xb  = (u16*)p; p += (size_t)B_ * S_ * D_ * 2;
  u16* Wqb = (u16*)p; p += (size_t)D_ * D_ * 2;   // Wq/Wk/Wv contiguous -> packed [6144][2048]
  u16* Wkb = (u16*)p; p += (size_t)D_ * D_ * 2;
  u16* Wvb = (u16*)p; p += (size_t)D_ * D_ * 2;
  u16* Wob = (u16*)p; p += (size_t)D_ * D_ * 2;
  u16* Qb  = (u16*)p; p += (size_t)B_ * S_ * D_ * 2;
  u16* Kb  = (u16*)p; p += (size_t)B_ * S_ * D_ * 2;
  u16* Vb  = (u16*)p; p += (size_t)B_ * S_ * D_ * 2;
  float2* tab = (float2*)p; p += (size_t)S_ * 64 * sizeof(float2);
  float2* ml  = (float2*)p; p += (size_t)2 * B_ * H_ * S_ * sizeof(float2);
  // partial-O buffers reuse dead regions: xb (dead after gemm_qkv3) and
  // Wqb+Wkb (dead after gemm_qkv3; exactly B*S*D*2 bytes combined).
  u16* po0 = xb;
  u16* po1 = Wqb;
  u16* Ob  = Qb;  // combined attention output overwrites Q (attn reads Q first)

  const int nx = B_ * S_ * D_;
  const int nw = D_ * D_;
  cvt_f32_bf16<<<nx / 1024, 256, 0, stream>>>(x,  xb,  nx);
  cvt_f32_bf16<<<nw / 1024, 256, 0, stream>>>(Wq, Wqb, nw);
  cvt_f32_bf16<<<nw / 1024, 256, 0, stream>>>(Wk, Wkb, nw);
  cvt_f32_bf16<<<nw / 1024, 256, 0, stream>>>(Wv, Wvb, nw);
  cvt_f32_bf16<<<nw / 1024, 256, 0, stream>>>(Wo, Wob, nw);
  rope_table<<<(S_ * 64) / 256, 256, 0, stream>>>(pos, tab);

  // fused QKV projection: one dispatch, N=6144 over packed weights
  gemm_qkv3<<<dim3(B_ * S_ / 128, 48), 256, 0, stream>>>(xb, Wqb, Qb, Kb, Vb);

  rope_apply<<<(B_ * S_ * H_ * 16) / 256, 256, 0, stream>>>(Qb, Kb, tab);

  // KV-split flash attention + combine
  attn_fwd<<<dim3(16, B_ * H_, 2), 256, 0, stream>>>(Qb, Kb, Vb, po0, po1, ml);
  attn_combine<<<(B_ * H_ * S_ * 16) / 256, 256, 0, stream>>>(po0, po1, ml, Ob);

  gemm_bt<true><<<dim3(B_ * S_ / 128, D_ / 128), 256, 0, stream>>>(Ob, Wob, (float*)d_out, B_ * S_, D_, D_);
}